// Round 1
// baseline (25029.366 us; speedup 1.0000x reference)
//
#include <hip/hip_runtime.h>
#include <hip/hip_bf16.h>

// Problem constants
#define LP   512
#define LQ   256
#define BB   32
#define INN  512
#define HH   150
#define K3   450   // 3*H

__device__ __forceinline__ float sigm(float x){ return 1.0f/(1.0f+__expf(-x)); }
__device__ __forceinline__ float ftanh(float x){ float e=__expf(2.0f*x); return 1.0f - 2.0f/(e+1.0f); }

__device__ __forceinline__ float wredmax(float v){
  #pragma unroll
  for(int o=1;o<64;o<<=1) v = fmaxf(v, __shfl_xor(v,o,64));
  return v;
}
__device__ __forceinline__ float wredsum(float v){
  #pragma unroll
  for(int o=1;o<64;o<<=1) v += __shfl_xor(v,o,64);
  return v;
}

// ---------------- weight folding (one-time) ----------------
// WpT[i*150+h] = Wp[h,i]+Wp[h,i+512]   (transposed effective, for GEMM)
// WqT likewise. WgupT[i*1024+j] = Wg[1024+j,i]+Wg[1024+j,512+i]
// Wgc[j*512+i] = Wg[1024+j,1024+i]+Wg[1024+j,1536+i]  (row-major per j)
// WvT[a*150+c] = Wv[c,a]
__global__ void k_fold(const float* __restrict__ Wp, const float* __restrict__ Wq,
                       const float* __restrict__ Wg, const float* __restrict__ Wv,
                       float* __restrict__ WpT, float* __restrict__ WqT,
                       float* __restrict__ WgupT, float* __restrict__ Wgc,
                       float* __restrict__ WvT)
{
  int i0 = blockIdx.x*blockDim.x+threadIdx.x;
  int st = gridDim.x*blockDim.x;
  for(int o=i0;o<512*150;o+=st){ int h=o%150, i=o/150;
    WpT[o]=Wp[h*1024+i]+Wp[h*1024+512+i];
    WqT[o]=Wq[h*1024+i]+Wq[h*1024+512+i]; }
  for(int o=i0;o<512*1024;o+=st){ int i=o&511, j=o>>9;
    size_t rb=(size_t)(1024+j)*2048;
    WgupT[(size_t)i*1024+j]=Wg[rb+i]+Wg[rb+512+i];
    Wgc[o]=Wg[rb+1024+i]+Wg[rb+1536+i]; }
  for(int o=i0;o<150*150;o+=st){ int a=o/150, c=o%150;
    WvT[o]=Wv[c*150+a]; }
}

// ---------------- precompute GEMMs ----------------
// C[m][n] = sum_k A[m*512+k]*WT[k*N+n],  32-row m tiles, K=512 fixed.
// MODE 0: oF[m*N+n]          (Wup: m=t*32+b, n=h)
// MODE 1: oB[(mt*1024+n)*32+mm] bf16  (Gup[t][j][b], N=1024)
// MODE 2: oF[(mm*150+n)*256+mt]       (WqUqT[b][h][q], M=8192 so mt=q, mm=b)
template<int MODE>
__global__ __launch_bounds__(256) void k_gemm(const float* __restrict__ A,
   const float* __restrict__ WT, float* __restrict__ oF,
   __hip_bfloat16* __restrict__ oB, int N)
{
  __shared__ float Al[32*512];
  int mt=blockIdx.x, nt=blockIdx.y, tid=threadIdx.x;
  const float* Ab = A + (size_t)mt*16384;
  for(int o=tid;o<4096;o+=256) ((float4*)Al)[o]=((const float4*)Ab)[o];
  __syncthreads();
  int n = nt*256+tid;
  if(n>=N) return;
  float acc[32];
  #pragma unroll
  for(int m=0;m<32;m++) acc[m]=0.f;
  const float* wp = WT + n;
  #pragma unroll 2
  for(int k=0;k<512;k+=2){
    float w0 = wp[(size_t)k*N], w1 = wp[(size_t)(k+1)*N];
    #pragma unroll
    for(int m=0;m<32;m++) acc[m]=fmaf(w0, Al[m*512+k], acc[m]);
    #pragma unroll
    for(int m=0;m<32;m++) acc[m]=fmaf(w1, Al[m*512+k+1], acc[m]);
  }
  if(MODE==0){
    #pragma unroll
    for(int m=0;m<32;m++) oF[(size_t)(mt*32+m)*N + n] = acc[m];
  } else if(MODE==1){
    #pragma unroll
    for(int m=0;m<32;m++) oB[((size_t)mt*1024+n)*32+m] = __float2bfloat16(acc[m]);
  } else {
    #pragma unroll
    for(int m=0;m<32;m++) oF[((size_t)m*150+n)*256+mt] = acc[m];
  }
}

// ---------------- per-step kernel A: GRU-finalize (elementwise) + vWv + s ----------------
// grid 64 = 2 WGs per b (qs in {0,1}); block 256
__global__ __launch_bounds__(256) void k_A(
  const float* __restrict__ Wup, const float* __restrict__ WqUqT,
  const float* __restrict__ WvT, const float* __restrict__ Vm,
  const float* __restrict__ v0, const float* __restrict__ giP,
  const float* __restrict__ gh_g, const float* __restrict__ b_ih,
  float* __restrict__ vbuf, float* __restrict__ s_g,
  float* __restrict__ dout, int t)
{
  int b = blockIdx.x & 31, qs = blockIdx.x >> 5;
  int tid = threadIdx.x;
  __shared__ float vst[150], w2[150], Vb[150];
  if(tid<150){
    float vn;
    if(t==0){ vn = v0[b*150+tid]; }
    else {
      float vo = vbuf[((t-1)&1)*4800 + b*150+tid];
      float ir = giP[b*450+tid]     + giP[(32+b)*450+tid]     + b_ih[tid];
      float iz = giP[b*450+150+tid] + giP[(32+b)*450+150+tid] + b_ih[150+tid];
      float inn= giP[b*450+300+tid] + giP[(32+b)*450+300+tid] + b_ih[300+tid];
      float hr = gh_g[b*450+tid], hz = gh_g[b*450+150+tid], hn = gh_g[b*450+300+tid];
      float rg = sigm(ir+hr), zg = sigm(iz+hz);
      float ng = ftanh(inn + rg*hn);
      vn = (1.f-zg)*ng + zg*vo;
      if(qs==0) dout[(size_t)(t-1)*4800 + b*150+tid] = vn;
    }
    vst[tid]=vn;
    if(qs==0) vbuf[(t&1)*4800 + b*150+tid] = vn;
    Vb[tid] = Vm[b*150+tid];
  }
  __syncthreads();
  if(tid<150){
    float acc = Wup[((size_t)t*32+b)*150 + tid];
    for(int kk=0;kk<150;kk++) acc = fmaf(WvT[kk*150+tid], vst[kk], acc);
    w2[tid]=acc;
  }
  __syncthreads();
  int q = qs*128 + (tid>>1);
  int hc = tid&1;
  const float* wq = WqUqT + (size_t)b*150*256;
  float acc=0.f;
  for(int h=hc; h<150; h+=2)
    acc += ftanh(w2[h] + wq[(size_t)h*256+q]) * Vb[h];
  acc += __shfl_xor(acc,1,64);
  if(hc==0) s_g[b*256+q] = acc;
}

// ---------------- per-step kernel BC: softmax + cc ----------------
// grid 256: b=blk&31, isl=blk>>5 (64 i per WG); block 256
__global__ __launch_bounds__(256) void k_BC(const float* __restrict__ s_g,
   const float* __restrict__ uq, float* __restrict__ cc_g)
{
  int b = blockIdx.x&31, isl = blockIdx.x>>5;
  int tid = threadIdx.x;
  __shared__ float a_l[256], red[256], red4[4];
  float sv = s_g[b*256+tid];
  float wm = wredmax(sv);
  if((tid&63)==0) red4[tid>>6]=wm;
  __syncthreads();
  float m = fmaxf(fmaxf(red4[0],red4[1]),fmaxf(red4[2],red4[3]));
  float e = __expf(sv-m);
  float wsum = wredsum(e);
  __syncthreads();
  if((tid&63)==0) red4[tid>>6]=wsum;
  __syncthreads();
  float S = red4[0]+red4[1]+red4[2]+red4[3];
  a_l[tid] = e/S;
  __syncthreads();
  int il = tid&63, qc = tid>>6;
  int i = isl*64 + il;
  const float* uqp = uq + (size_t)(qc*64)*16384 + (size_t)b*512 + i;
  float acc=0.f;
  #pragma unroll 4
  for(int k=0;k<64;k++) acc = fmaf(a_l[qc*64+k], uqp[(size_t)k*16384], acc);
  red[tid]=acc;
  __syncthreads();
  if(tid<64){
    float c = red[tid]+red[tid+64]+red[tid+128]+red[tid+192];
    cc_g[(isl*64+tid)*32+b] = c;
  }
}

// ---------------- per-step kernel D: Gc -> gate -> c_ ----------------
// grid 128 x 512 threads: wave per j (j=blk*8+wave), lanes = (b, i-half)
__global__ __launch_bounds__(512) void k_D(const float* __restrict__ cc_g,
    const float* __restrict__ Wgc, const __hip_bfloat16* __restrict__ Gup,
    const float* __restrict__ up, const float* __restrict__ WgupT,
    float* __restrict__ c_g, int t, int hasGup)
{
  __shared__ float cl[16384];  // cc[i][b] fp32, 64KB
  int tid=threadIdx.x;
  for(int o=tid;o<16384;o+=512) cl[o]=cc_g[o];
  __syncthreads();
  int wv=tid>>6, l=tid&63, b=l&31, ih=l>>5;
  int j = blockIdx.x*8+wv;
  const float4* wr = (const float4*)(Wgc + (size_t)j*512 + ih*256);
  float acc=0.f;
  #pragma unroll 4
  for(int kk=0;kk<64;kk++){
    float4 w = wr[kk];
    int base = (ih*256+kk*4)*32 + b;
    acc = fmaf(w.x, cl[base],    acc);
    acc = fmaf(w.y, cl[base+32], acc);
    acc = fmaf(w.z, cl[base+64], acc);
    acc = fmaf(w.w, cl[base+96], acc);
  }
  if(!hasGup){
    const float* ub = up + ((size_t)t*32+b)*512 + ih*256;
    const float* wg = WgupT + j + (size_t)(ih*256)*1024;
    for(int kk=0;kk<256;kk++) acc = fmaf(ub[kk], wg[(size_t)kk*1024], acc);
  }
  acc += __shfl_xor(acc, 32, 64);
  float gin = acc + (hasGup ? (float)Gup[((size_t)t*1024+j)*32+b] : 0.f);
  float g = sigm(gin);
  float cj = cl[(j&511)*32+b];
  if(l<32) c_g[(size_t)j*32+b] = g*cj;
}

// ---------------- per-step kernel E: gi partials + gh ----------------
// grid 114 x 512: half=blk&1 (K-split), wave per k (k=(blk>>1)*8+wave)
__global__ __launch_bounds__(512) void k_E(const float* __restrict__ c_g,
   const float* __restrict__ W_ih, const float* __restrict__ W_hh,
   const float* __restrict__ b_hh, const float* __restrict__ vbuf,
   float* __restrict__ giP, float* __restrict__ gh_g, int t)
{
  __shared__ float cl[16384];  // c_[j][b] for this half, 64KB
  int tid=threadIdx.x;
  int half = blockIdx.x & 1;
  for(int o=tid;o<16384;o+=512) cl[o] = c_g[half*16384 + o];
  __syncthreads();
  int wv=tid>>6, l=tid&63, b=l&31, jh=l>>5;
  int k = (blockIdx.x>>1)*8 + wv;
  if(k>=450) return;
  const float4* wr = (const float4*)(W_ih + (size_t)k*1024 + half*512 + jh*256);
  float acc=0.f;
  #pragma unroll 4
  for(int kk=0;kk<64;kk++){
    float4 w = wr[kk];
    int base = (jh*256+kk*4)*32 + b;
    acc = fmaf(w.x, cl[base],    acc);
    acc = fmaf(w.y, cl[base+32], acc);
    acc = fmaf(w.z, cl[base+64], acc);
    acc = fmaf(w.w, cl[base+96], acc);
  }
  acc += __shfl_xor(acc,32,64);
  if(l<32) giP[((size_t)half*32+b)*450 + k] = acc;
  if(half==0){
    const float* vr = vbuf + (t&1)*4800 + b*150 + jh*75;
    const float* wh = W_hh + k*150 + jh*75;
    float ah=0.f;
    for(int m=0;m<75;m++) ah = fmaf(wh[m], vr[m], ah);
    ah += __shfl_xor(ah,32,64);
    if(l<32) gh_g[b*450+k] = ah + b_hh[k];
  }
}

// ---------------- final GRU (writes vs[511]) ----------------
__global__ void k_F(const float* __restrict__ giP, const float* __restrict__ gh_g,
                    const float* __restrict__ b_ih, const float* __restrict__ vbuf,
                    float* __restrict__ dout)
{
  int b=blockIdx.x, h=threadIdx.x;
  if(h>=150) return;
  float vo = vbuf[1*4800 + b*150+h];   // v_511 (slot 511&1)
  float ir = giP[b*450+h]     + giP[(32+b)*450+h]     + b_ih[h];
  float iz = giP[b*450+150+h] + giP[(32+b)*450+150+h] + b_ih[150+h];
  float inn= giP[b*450+300+h] + giP[(32+b)*450+300+h] + b_ih[300+h];
  float hr = gh_g[b*450+h], hz = gh_g[b*450+150+h], hn = gh_g[b*450+300+h];
  float rg = sigm(ir+hr), zg = sigm(iz+hz);
  float ng = ftanh(inn + rg*hn);
  dout[(size_t)511*4800 + b*150+h] = (1.f-zg)*ng + zg*vo;
}

// ---------------- host ----------------
extern "C" void kernel_launch(void* const* d_in, const int* in_sizes, int n_in,
                              void* d_out, int out_size, void* d_ws, size_t ws_size,
                              hipStream_t stream)
{
  const float* up  = (const float*)d_in[0];
  const float* uq  = (const float*)d_in[1];
  const float* v0  = (const float*)d_in[2];
  const float* Vm  = (const float*)d_in[3];
  const float* Wp  = (const float*)d_in[4];
  const float* Wq  = (const float*)d_in[5];
  const float* Wv  = (const float*)d_in[6];
  const float* Wg  = (const float*)d_in[7];
  const float* W_ih= (const float*)d_in[8];
  const float* W_hh= (const float*)d_in[9];
  const float* b_ih= (const float*)d_in[10];
  const float* b_hh= (const float*)d_in[11];
  float* dout = (float*)d_out;
  float* ws = (float*)d_ws;

  // workspace layout (float offsets)
  float* WpT   = ws + 0;         // 76800
  float* WqT   = ws + 76800;     // 76800
  float* WgupT = ws + 153600;    // 524288
  float* Wgc   = ws + 677888;    // 524288
  float* WvT   = ws + 1202176;   // 22500
  float* Wup   = ws + 1224676;   // 2457600
  float* WqUqT = ws + 3682276;   // 1228800
  float* s_g   = ws + 4911076;   // 8192
  float* cc_g  = ws + 4919268;   // 16384
  float* c_g   = ws + 4935652;   // 32768
  float* giP   = ws + 4968420;   // 28800
  float* gh_g  = ws + 4997220;   // 14400
  float* vbuf  = ws + 5011620;   // 9600
  // Gup (bf16) tail: 512*1024*32 elements
  __hip_bfloat16* Gup = (__hip_bfloat16*)(ws + 5021220);
  const size_t needCore = (size_t)5021220*4;
  const size_t needFull = needCore + (size_t)512*1024*32*2;
  if(ws_size < needCore) return;  // cannot run without core scratch
  int hasGup = (ws_size >= needFull) ? 1 : 0;

  // one-time folds + precompute GEMMs
  k_fold<<<512,256,0,stream>>>(Wp,Wq,Wg,Wv, WpT,WqT,WgupT,Wgc,WvT);
  k_gemm<0><<<dim3(512,1),256,0,stream>>>(up, WpT, Wup, nullptr, 150);
  k_gemm<2><<<dim3(256,1),256,0,stream>>>(uq, WqT, WqUqT, nullptr, 150);
  if(hasGup)
    k_gemm<1><<<dim3(512,4),256,0,stream>>>(up, WgupT, nullptr, Gup, 1024);

  for(int t=0;t<512;t++){
    k_A <<<64,256,0,stream>>>(Wup, WqUqT, WvT, Vm, v0, giP, gh_g, b_ih, vbuf, s_g, dout, t);
    k_BC<<<256,256,0,stream>>>(s_g, uq, cc_g);
    k_D <<<128,512,0,stream>>>(cc_g, Wgc, Gup, up, WgupT, c_g, t, hasGup);
    k_E <<<114,512,0,stream>>>(c_g, W_ih, W_hh, b_hh, vbuf, giP, gh_g, t);
  }
  k_F<<<32,192,0,stream>>>(giP, gh_g, b_ih, vbuf, dout);
}

// Round 2
// 21054.454 us; speedup vs baseline: 1.1888x; 1.1888x over previous
//
#include <hip/hip_runtime.h>
#include <hip/hip_bf16.h>

#define AGENT __HIP_MEMORY_SCOPE_AGENT

__device__ __forceinline__ float sigm(float x){ return 1.0f/(1.0f+__expf(-x)); }
__device__ __forceinline__ float ftanh(float x){ float e=__expf(2.0f*x); return 1.0f - 2.0f/(e+1.0f); }
__device__ __forceinline__ unsigned short f2b(float f){
  union{float f;unsigned u;}c; c.f=f; unsigned r = c.u + 0x7FFF + ((c.u>>16)&1); return (unsigned short)(r>>16);
}
__device__ __forceinline__ float b2f(unsigned short b){
  union{unsigned u;float f;}c; c.u = ((unsigned)b)<<16; return c.f;
}
__device__ __forceinline__ float wredmax(float v){
  #pragma unroll
  for(int o=1;o<64;o<<=1) v = fmaxf(v, __shfl_xor(v,o,64));
  return v;
}
__device__ __forceinline__ float wredsum(float v){
  #pragma unroll
  for(int o=1;o<64;o<<=1) v += __shfl_xor(v,o,64);
  return v;
}

// ---------------- one-time weight folds ----------------
__global__ void k_fold(const float* __restrict__ Wp, const float* __restrict__ Wq,
                       const float* __restrict__ Wg,
                       float* __restrict__ WpT, float* __restrict__ WqT,
                       float* __restrict__ WgupT)
{
  int i0 = blockIdx.x*blockDim.x+threadIdx.x;
  int st = gridDim.x*blockDim.x;
  for(int o=i0;o<512*150;o+=st){ int h=o%150, i=o/150;
    WpT[o]=Wp[h*1024+i]+Wp[h*1024+512+i];
    WqT[o]=Wq[h*1024+i]+Wq[h*1024+512+i]; }
  for(int o=i0;o<512*1024;o+=st){ int i=o&511, j=o>>9;
    size_t rb=(size_t)(1024+j)*2048;
    WgupT[(size_t)i*1024+j]=Wg[rb+i]+Wg[rb+512+i]; }
}

// ---------------- precompute GEMMs (as in R1, validated) ----------------
template<int MODE>
__global__ __launch_bounds__(256) void k_gemm(const float* __restrict__ A,
   const float* __restrict__ WT, float* __restrict__ oF,
   __hip_bfloat16* __restrict__ oB, int N)
{
  __shared__ float Al[32*512];
  int mt=blockIdx.x, nt=blockIdx.y, tid=threadIdx.x;
  const float* Ab = A + (size_t)mt*16384;
  for(int o=tid;o<4096;o+=256) ((float4*)Al)[o]=((const float4*)Ab)[o];
  __syncthreads();
  int n = nt*256+tid;
  if(n>=N) return;
  float acc[32];
  #pragma unroll
  for(int m=0;m<32;m++) acc[m]=0.f;
  const float* wp = WT + n;
  #pragma unroll 2
  for(int k=0;k<512;k+=2){
    float w0 = wp[(size_t)k*N], w1 = wp[(size_t)(k+1)*N];
    #pragma unroll
    for(int m=0;m<32;m++) acc[m]=fmaf(w0, Al[m*512+k], acc[m]);
    #pragma unroll
    for(int m=0;m<32;m++) acc[m]=fmaf(w1, Al[m*512+k+1], acc[m]);
  }
  if(MODE==0){
    #pragma unroll
    for(int m=0;m<32;m++) oF[(size_t)(mt*32+m)*N + n] = acc[m];
  } else if(MODE==1){
    #pragma unroll
    for(int m=0;m<32;m++) oB[((size_t)mt*1024+n)*32+m] = __float2bfloat16(acc[m]);
  } else {
    #pragma unroll
    for(int m=0;m<32;m++) oF[((size_t)m*150+n)*256+mt] = acc[m];
  }
}

__global__ void k_init(unsigned* ctr){ ctr[threadIdx.x] = 0u; }

// ---------------- persistent cooperative kernel ----------------
struct SMem {
  float v_l[4][152];
  float V_l[4][152];
  float w2_l[8][4];
  float red_s[520];     // also used as float2[260]
  float red4[8];
  float sa_l[256];
  float gi_l[16][4];
  float gh_l[16][4];
  union { float cc_t[4][516]; unsigned cJ[4][516]; } cx;
  unsigned short WqUq_l[5][256][4];   // [hi][q][bl] bf16
  unsigned short uq_l[256][64];       // [q][i_loc] bf16
  unsigned short Wgc_l[32][514];      // [jl][i] bf16 (pad 514)
  unsigned short Wih_l[15][1028];     // [kr][i] bf16 (pad 1028)
  unsigned short Whh_l[15][152];
  unsigned short Wv_l[5][152];
};

__device__ __forceinline__ void gbar(unsigned* c, unsigned target){
  __syncthreads();
  if(threadIdx.x==0){
    __hip_atomic_fetch_add(c, 1u, __ATOMIC_ACQ_REL, AGENT);
    long spins=0;
    while(__hip_atomic_load(c, __ATOMIC_ACQUIRE, AGENT) < target){
      __builtin_amdgcn_s_sleep(2);
      if(++spins > 200000000L) break;   // bail out instead of hanging forever
    }
  }
  __syncthreads();
}

__global__ __launch_bounds__(512) void persist(
  const float* __restrict__ uq, const float* __restrict__ v0,
  const float* __restrict__ Vin, const float* __restrict__ Wv,
  const float* __restrict__ Wg, const float* __restrict__ Wih,
  const float* __restrict__ Whh, const float* __restrict__ bih,
  const float* __restrict__ bhh, const float* __restrict__ Wup,
  const float* __restrict__ WqUqT, const unsigned short* __restrict__ Gup,
  float* sP, float* ccw, unsigned* cjw, float* vbuf, unsigned* ctr,
  float* __restrict__ dout)
{
  extern __shared__ char smem_raw[];
  SMem& S = *reinterpret_cast<SMem*>(smem_raw);

  const int tid = threadIdx.x;
  const int bid = blockIdx.x;
  const int gid = bid >> 5;          // 8 groups
  const int lid = bid & 31;          // 32 blocks per group
  const int b0  = gid*4;             // 4 batch elems per group
  const int hs  = (lid*150) >> 5;    // h-slice for phases A and D
  const int he  = ((lid+1)*150) >> 5;
  const int nh  = he - hs;           // 4 or 5
  const int bB  = lid >> 3;          // phase B: owned b (0..3)
  const int isl = lid & 7;           // phase B: i-slice (64 wide)
  const int j0  = lid * 32;          // phase C: j-slice
  unsigned* myctr = ctr + gid*64;

  // ================= prologue: pin LDS slices (bf16) =================
  for(int o=tid;o<600;o+=512){ int bl=o/150,c=o%150;
    S.v_l[bl][c] = v0[(b0+bl)*150+c];
    S.V_l[bl][c] = Vin[(b0+bl)*150+c]; }
  for(int o=tid;o<nh*1024;o+=512){ int hi=o>>10, bl=(o>>8)&3, q=o&255;
    S.WqUq_l[hi][q][bl] = f2b(WqUqT[((size_t)(b0+bl)*150 + hs+hi)*256 + q]); }
  for(int o=tid;o<16384;o+=512){ int q=o>>6, il=o&63;
    S.uq_l[q][il] = f2b(uq[((size_t)q*32 + (b0+bB))*512 + isl*64 + il]); }
  for(int o=tid;o<16384;o+=512){ int jl=o>>9, i=o&511;
    size_t rb=(size_t)(1024 + j0+jl)*2048;
    S.Wgc_l[jl][i] = f2b(Wg[rb+1024+i] + Wg[rb+1536+i]); }
  for(int o=tid;o<nh*3*1024;o+=512){ int kr=o>>10, i=o&1023;
    int k = (kr%3)*150 + hs + kr/3;
    S.Wih_l[kr][i] = f2b(Wih[(size_t)k*1024 + i]); }
  for(int o=tid;o<nh*3*150;o+=512){ int kr=o/150, c=o%150;
    int k = (kr%3)*150 + hs + kr/3;
    S.Whh_l[kr][c] = f2b(Whh[k*150 + c]); }
  for(int o=tid;o<nh*150;o+=512){ int hi=o/150, c=o%150;
    S.Wv_l[hi][c] = f2b(Wv[(hs+hi)*150 + c]); }
  __syncthreads();

  // ================= 512-step scan =================
  for(int t=0; t<512; t++){
    // ---------- phase A: v reload, w2 = Wup + v*Wv^T, s-partials ----------
    if(t>0){
      for(int o=tid;o<600;o+=512){ int bl=o/150,c=o%150;
        S.v_l[bl][c] = __hip_atomic_load(&vbuf[(b0+bl)*150+c], __ATOMIC_RELAXED, AGENT); }
      __syncthreads();
    }
    {
      int hb = tid>>4, ch = tid&15;
      int bl = hb&3, hi = hb>>2;
      float acc = 0.f;
      if(hi<nh){
        int c0=(ch*150)>>4, c1=((ch+1)*150)>>4;
        for(int c=c0;c<c1;c++) acc = fmaf(b2f(S.Wv_l[hi][c]), S.v_l[bl][c], acc);
      }
      acc += __shfl_xor(acc,1,64); acc += __shfl_xor(acc,2,64);
      acc += __shfl_xor(acc,4,64); acc += __shfl_xor(acc,8,64);
      if(hi<nh && ch==0)
        S.w2_l[hi][bl] = acc + Wup[((size_t)t*32 + b0+bl)*150 + hs+hi];
    }
    __syncthreads();
    if(tid<256){
      int q = tid;
      float sacc[4] = {0.f,0.f,0.f,0.f};
      for(int hi=0;hi<nh;hi++){
        ushort4 wq4 = *(const ushort4*)&S.WqUq_l[hi][q][0];
        float x0 = ftanh(S.w2_l[hi][0] + b2f(wq4.x));
        float x1 = ftanh(S.w2_l[hi][1] + b2f(wq4.y));
        float x2 = ftanh(S.w2_l[hi][2] + b2f(wq4.z));
        float x3 = ftanh(S.w2_l[hi][3] + b2f(wq4.w));
        int h = hs+hi;
        sacc[0] = fmaf(S.V_l[0][h], x0, sacc[0]);
        sacc[1] = fmaf(S.V_l[1][h], x1, sacc[1]);
        sacc[2] = fmaf(S.V_l[2][h], x2, sacc[2]);
        sacc[3] = fmaf(S.V_l[3][h], x3, sacc[3]);
      }
      #pragma unroll
      for(int bl=0;bl<4;bl++)
        __hip_atomic_store(&sP[((size_t)(b0+bl)*32 + lid)*256 + q], sacc[bl], __ATOMIC_RELAXED, AGENT);
    }
    gbar(myctr, (unsigned)(t*4+1)*32);

    // ---------- phase B: s-reduce, softmax, cc ----------
    {
      int q = tid&255, lh = tid>>8;
      float ps = 0.f;
      size_t base = ((size_t)(b0+bB)*32 + lh*16)*256 + q;
      for(int l=0;l<16;l++)
        ps += __hip_atomic_load(&sP[base + (size_t)l*256], __ATOMIC_RELAXED, AGENT);
      S.red_s[tid] = ps;
    }
    __syncthreads();
    {
      float sfull=0.f, e=0.f;
      if(tid<256) sfull = S.red_s[tid] + S.red_s[tid+256];
      if(tid<256){ float m0=wredmax(sfull); if((tid&63)==0) S.red4[tid>>6]=m0; }
      __syncthreads();
      if(tid<256){
        float m = fmaxf(fmaxf(S.red4[0],S.red4[1]),fmaxf(S.red4[2],S.red4[3]));
        e = __expf(sfull - m);
        float s0 = wredsum(e);
        if((tid&63)==0) S.red4[4+(tid>>6)] = s0;
      }
      __syncthreads();
      if(tid<256){
        float Ssum = S.red4[4]+S.red4[5]+S.red4[6]+S.red4[7];
        S.sa_l[tid] = e / Ssum;
      }
    }
    __syncthreads();
    {
      int ip = tid&31, qc = tid>>5;       // 16 chunks of 16 q
      float c0=0.f, c1=0.f;
      for(int k=0;k<16;k++){
        int q = qc*16 + k;
        float av = S.sa_l[q];
        unsigned u = *(const unsigned*)&S.uq_l[q][ip*2];
        c0 = fmaf(av, b2f((unsigned short)(u&0xFFFF)), c0);
        c1 = fmaf(av, b2f((unsigned short)(u>>16)), c1);
      }
      c0 += __shfl_xor(c0,32,64); c1 += __shfl_xor(c1,32,64);
      float2* red2 = (float2*)S.red_s;
      if((tid&32)==0) red2[(tid>>6)*32 + ip] = make_float2(c0,c1);
      __syncthreads();
      if(tid<32){
        float a0=0.f,a1=0.f;
        for(int k=0;k<8;k++){ float2 v = red2[k*32+tid]; a0+=v.x; a1+=v.y; }
        size_t cb = ((size_t)(gid*4+bB))*512 + isl*64 + tid*2;
        __hip_atomic_store(&ccw[cb],   a0, __ATOMIC_RELAXED, AGENT);
        __hip_atomic_store(&ccw[cb+1], a1, __ATOMIC_RELAXED, AGENT);
      }
    }
    gbar(myctr, (unsigned)(t*4+2)*32);

    // ---------- phase C: gate -> c_ ----------
    for(int o=tid;o<2048;o+=512){ int bl=o>>9, i=o&511;
      S.cx.cc_t[bl][i] = __hip_atomic_load(&ccw[(size_t)gid*2048 + o], __ATOMIC_RELAXED, AGENT); }
    __syncthreads();
    {
      int quarter = tid&3; int o = tid>>2;      // 128 outputs
      int bl = o&3, jl = o>>2;
      const unsigned* wgc = (const unsigned*)&S.Wgc_l[jl][0];
      float acc = 0.f;
      for(int st=0; st<64; st++){
        int ip = st*4 + quarter;
        unsigned w = wgc[ip];
        float2 c2 = *(const float2*)&S.cx.cc_t[bl][2*ip];
        acc = fmaf(b2f((unsigned short)(w&0xFFFF)), c2.x, acc);
        acc = fmaf(b2f((unsigned short)(w>>16)),    c2.y, acc);
      }
      acc += __shfl_xor(acc,1,64); acc += __shfl_xor(acc,2,64);
      float val = 0.f;
      int j = j0 + jl;
      if(quarter==0){
        float gup = b2f(Gup[((size_t)t*1024 + j)*32 + (b0+bl)]);
        float g = sigm(acc + gup);
        val = g * S.cx.cc_t[bl][j&511];
      }
      float vo = __shfl_xor(val, 16, 64);   // partner jl^1
      if(quarter==0 && ((jl&1)==0)){
        unsigned u = (unsigned)f2b(val) | ((unsigned)f2b(vo)<<16);
        __hip_atomic_store(&cjw[((size_t)(gid*4+bl))*512 + lid*16 + (jl>>1)], u, __ATOMIC_RELAXED, AGENT);
      }
    }
    gbar(myctr, (unsigned)(t*4+3)*32);

    // ---------- phase D: gi, gh, GRU finalize ----------
    for(int o=tid;o<2048;o+=512){ int bl=o>>9, jp=o&511;
      S.cx.cJ[bl][jp] = __hip_atomic_load(&cjw[(size_t)gid*2048 + o], __ATOMIC_RELAXED, AGENT); }
    __syncthreads();
    {
      int sp = tid&7; int o = tid>>3;        // 64 slots: kr 0..15 x bl 0..3
      int bl = o&3, kr = o>>2;
      if(kr < 3*nh){
        const unsigned* wih = (const unsigned*)&S.Wih_l[kr][0];
        float acc = 0.f;
        for(int st=0; st<64; st++){
          int jp = st*8 + sp;
          unsigned cw = S.cx.cJ[bl][jp];
          unsigned ww = wih[jp];
          acc = fmaf(b2f((unsigned short)(ww&0xFFFF)), b2f((unsigned short)(cw&0xFFFF)), acc);
          acc = fmaf(b2f((unsigned short)(ww>>16)),    b2f((unsigned short)(cw>>16)),    acc);
        }
        float gh = 0.f;
        for(int c=sp; c<150; c+=8)
          gh = fmaf(b2f(S.Whh_l[kr][c]), S.v_l[bl][c], gh);
        acc += __shfl_xor(acc,1,64); acc += __shfl_xor(acc,2,64); acc += __shfl_xor(acc,4,64);
        gh  += __shfl_xor(gh,1,64);  gh  += __shfl_xor(gh,2,64);  gh  += __shfl_xor(gh,4,64);
        if(sp==0){ S.gi_l[kr][bl] = acc; S.gh_l[kr][bl] = gh; }
      }
    }
    __syncthreads();
    if(tid < 4*nh){
      int bl = tid&3, hi = tid>>2;
      int h = hs + hi;
      float ir = S.gi_l[hi*3+0][bl] + bih[h];
      float iz = S.gi_l[hi*3+1][bl] + bih[150+h];
      float in = S.gi_l[hi*3+2][bl] + bih[300+h];
      float hr = S.gh_l[hi*3+0][bl] + bhh[h];
      float hz = S.gh_l[hi*3+1][bl] + bhh[150+h];
      float hn = S.gh_l[hi*3+2][bl] + bhh[300+h];
      float rg = sigm(ir+hr), zg = sigm(iz+hz);
      float ng = ftanh(in + rg*hn);
      float vo = S.v_l[bl][h];
      float vn = (1.f-zg)*ng + zg*vo;
      __hip_atomic_store(&vbuf[(b0+bl)*150 + h], vn, __ATOMIC_RELAXED, AGENT);
      dout[((size_t)t*32 + b0+bl)*150 + h] = vn;
    }
    gbar(myctr, (unsigned)(t*4+4)*32);
  }
}

// ---------------- host ----------------
extern "C" void kernel_launch(void* const* d_in, const int* in_sizes, int n_in,
                              void* d_out, int out_size, void* d_ws, size_t ws_size,
                              hipStream_t stream)
{
  const float* up  = (const float*)d_in[0];
  const float* uq  = (const float*)d_in[1];
  const float* v0  = (const float*)d_in[2];
  const float* Vm  = (const float*)d_in[3];
  const float* Wp  = (const float*)d_in[4];
  const float* Wq  = (const float*)d_in[5];
  const float* Wv  = (const float*)d_in[6];
  const float* Wg  = (const float*)d_in[7];
  const float* W_ih= (const float*)d_in[8];
  const float* W_hh= (const float*)d_in[9];
  const float* b_ih= (const float*)d_in[10];
  const float* b_hh= (const float*)d_in[11];
  float* dout = (float*)d_out;
  float* ws = (float*)d_ws;

  float* WpT   = ws + 0;          // 76800
  float* WqT   = ws + 76800;      // 76800
  float* WgupT = ws + 153600;     // 524288
  float* Wup   = ws + 677888;     // 2457600
  float* WqUqT = ws + 3135488;    // 1228800
  float* sP    = ws + 4364288;    // 262144
  float* ccw   = ws + 4626432;    // 16384
  unsigned* cjw = (unsigned*)(ws + 4642816); // 16384 words
  float* vbuf  = ws + 4659200;    // 4800
  unsigned* ctr = (unsigned*)(ws + 4664000); // 512 words
  unsigned short* Gup = (unsigned short*)(ws + 4664512);
  size_t need = (size_t)4664512*4 + (size_t)512*1024*32*2;
  if(ws_size < need) return;

  k_init<<<1,512,0,stream>>>(ctr);
  k_fold<<<256,256,0,stream>>>(Wp,Wq,Wg, WpT,WqT,WgupT);
  k_gemm<0><<<dim3(512,1),256,0,stream>>>(up, WpT, Wup, nullptr, 150);
  k_gemm<2><<<dim3(256,1),256,0,stream>>>(uq, WqT, WqUqT, nullptr, 150);
  k_gemm<1><<<dim3(512,4),256,0,stream>>>(up, WgupT, nullptr, (__hip_bfloat16*)Gup, 1024);

  hipFuncSetAttribute((const void*)persist, hipFuncAttributeMaxDynamicSharedMemorySize, (int)sizeof(SMem));
  void* ka[18] = { (void*)&uq, (void*)&v0, (void*)&Vm, (void*)&Wv, (void*)&Wg,
                   (void*)&W_ih, (void*)&W_hh, (void*)&b_ih, (void*)&b_hh,
                   (void*)&Wup, (void*)&WqUqT, (void*)&Gup,
                   (void*)&sP, (void*)&ccw, (void*)&cjw, (void*)&vbuf, (void*)&ctr,
                   (void*)&dout };
  hipLaunchCooperativeKernel((const void*)persist, dim3(256), dim3(512), ka,
                             (unsigned)sizeof(SMem), stream);
}